// Round 1
// baseline (1429.973 us; speedup 1.0000x reference)
//
#include <hip/hip_runtime.h>
#include <hip/hip_bf16.h>

#define N_NODES 8000
#define N_EDGES 128000
#define RS8   0.35355339059327373f
#define RS64  0.125f
#define RS128 0.08838834764831845f
#define C1    0.005524271728019903f   /* (1/sqrt(128))/16 */
#define NORM  0.02795084971874737f    /* 1/sqrt(1280) */

__device__ __forceinline__ float siluf(float v){ return v / (1.f + __expf(-v)); }
__device__ __forceinline__ unsigned short f2bf(float v){
  unsigned int b = __float_as_uint(v);
  b += 0x7fffu + ((b >> 16) & 1u);
  return (unsigned short)(b >> 16);
}
__device__ __forceinline__ float bf2f(unsigned int h){
  union{unsigned int u; float f;} z; z.u = h << 16; return z.f;
}

// ---------------------------------------------------------------- K1: x = node_feats @ W_up * RS128
__global__ void __launch_bounds__(256) k_up(const float* __restrict__ nf,
                                            const float* __restrict__ Wup,
                                            float* __restrict__ x){
  __shared__ float f[2][128];
  const int t = threadIdx.x;
  const int nl = t >> 7, c = t & 127;
  const int n = blockIdx.x * 2 + nl;
  f[nl][c] = nf[(size_t)n * 128 + c];
  __syncthreads();
  float acc = 0.f;
  #pragma unroll 8
  for(int k = 0; k < 128; ++k) acc += f[nl][k] * Wup[k * 128 + c];
  x[(size_t)n * 128 + c] = acc * RS128;
}

// ---------------------------------------------------------------- K2: edge MLP -> tp_weights (bf16, cutoff folded)
__device__ __forceinline__ void gemm64(const float* __restrict__ hin, const float* __restrict__ Wb,
                                       int eb, int cb, float4 acc[4]){
  #pragma unroll
  for(int i = 0; i < 4; ++i) acc[i] = make_float4(0.f,0.f,0.f,0.f);
  #pragma unroll 2
  for(int k = 0; k < 64; k += 4){
    float4 w0 = *(const float4*)&Wb[(k+0)*64 + cb];
    float4 w1 = *(const float4*)&Wb[(k+1)*64 + cb];
    float4 w2 = *(const float4*)&Wb[(k+2)*64 + cb];
    float4 w3 = *(const float4*)&Wb[(k+3)*64 + cb];
    #pragma unroll
    for(int i = 0; i < 4; ++i){
      float4 h = *(const float4*)&hin[(eb+i)*64 + k];
      acc[i].x += h.x*w0.x + h.y*w1.x + h.z*w2.x + h.w*w3.x;
      acc[i].y += h.x*w0.y + h.y*w1.y + h.z*w2.y + h.w*w3.y;
      acc[i].z += h.x*w0.z + h.y*w1.z + h.z*w2.z + h.w*w3.z;
      acc[i].w += h.x*w0.w + h.y*w1.w + h.z*w2.w + h.w*w3.w;
    }
  }
}

__global__ void __launch_bounds__(256) k_mlp(
    const float* __restrict__ efg, const float* __restrict__ cut,
    const float* __restrict__ W1g, const float* __restrict__ W2g,
    const float* __restrict__ W3g, const float* __restrict__ W4g,
    __hip_bfloat16* __restrict__ tpw){
  __shared__ float ef[512];     // 64 edges x 8
  __shared__ float W1s[512];
  __shared__ float hA[4096];    // 64 x 64
  __shared__ float hB[4096];
  __shared__ float Wb[4096];
  __shared__ float co[64];
  const int t = threadIdx.x;
  const int e0 = blockIdx.x * 64;
  ((float2*)ef)[t]  = ((const float2*)(efg + (size_t)e0 * 8))[t];
  ((float2*)W1s)[t] = ((const float2*)W1g)[t];
  if(t < 64) co[t] = cut[e0 + t];
  __syncthreads();
  const int et = t >> 4, ct = t & 15;
  const int eb = et * 4, cb = ct * 4;
  // L1: (64x8)@(8x64) * RS8 -> silu -> hA
  {
    float4 acc[4];
    #pragma unroll
    for(int i = 0; i < 4; ++i) acc[i] = make_float4(0.f,0.f,0.f,0.f);
    #pragma unroll
    for(int k = 0; k < 8; ++k){
      float4 wv = *(const float4*)&W1s[k*64 + cb];
      #pragma unroll
      for(int i = 0; i < 4; ++i){
        float h = ef[(eb+i)*8 + k];
        acc[i].x += h*wv.x; acc[i].y += h*wv.y; acc[i].z += h*wv.z; acc[i].w += h*wv.w;
      }
    }
    #pragma unroll
    for(int i = 0; i < 4; ++i){
      float4 r;
      r.x = siluf(acc[i].x*RS8); r.y = siluf(acc[i].y*RS8);
      r.z = siluf(acc[i].z*RS8); r.w = siluf(acc[i].w*RS8);
      *(float4*)&hA[(eb+i)*64 + cb] = r;
    }
  }
  __syncthreads();
  #pragma unroll
  for(int r = 0; r < 8; ++r) ((float2*)Wb)[t + 256*r] = ((const float2*)W2g)[t + 256*r];
  __syncthreads();
  { // L2: hA -> hB
    float4 a[4]; gemm64(hA, Wb, eb, cb, a);
    #pragma unroll
    for(int i = 0; i < 4; ++i){
      float4 r;
      r.x = siluf(a[i].x*RS64); r.y = siluf(a[i].y*RS64);
      r.z = siluf(a[i].z*RS64); r.w = siluf(a[i].w*RS64);
      *(float4*)&hB[(eb+i)*64 + cb] = r;
    }
  }
  __syncthreads();
  #pragma unroll
  for(int r = 0; r < 8; ++r) ((float2*)Wb)[t + 256*r] = ((const float2*)W3g)[t + 256*r];
  __syncthreads();
  { // L3: hB -> hA
    float4 a[4]; gemm64(hB, Wb, eb, cb, a);
    #pragma unroll
    for(int i = 0; i < 4; ++i){
      float4 r;
      r.x = siluf(a[i].x*RS64); r.y = siluf(a[i].y*RS64);
      r.z = siluf(a[i].z*RS64); r.w = siluf(a[i].w*RS64);
      *(float4*)&hA[(eb+i)*64 + cb] = r;
    }
  }
  __syncthreads();
  // L4: hA(64x64) @ W4(64x512) in 8 chunks of 64 cols; *RS64*cutoff -> bf16
  for(int ch = 0; ch < 8; ++ch){
    #pragma unroll
    for(int r = 0; r < 16; ++r){
      int idx = t + 256*r;
      Wb[idx] = W4g[(idx >> 6) * 512 + ch * 64 + (idx & 63)];
    }
    __syncthreads();
    float4 a[4]; gemm64(hA, Wb, eb, cb, a);
    #pragma unroll
    for(int i = 0; i < 4; ++i){
      float cf = co[eb + i] * RS64;
      ushort4 pk;
      pk.x = f2bf(a[i].x * cf); pk.y = f2bf(a[i].y * cf);
      pk.z = f2bf(a[i].z * cf); pk.w = f2bf(a[i].w * cf);
      *(ushort4*)((unsigned short*)tpw + (size_t)(e0 + eb + i) * 512 + ch * 64 + cb) = pk;
    }
    __syncthreads();
  }
}

// ---------------------------------------------------------------- Wm[m][u][u'] = W_lin[l(m)][u][u'] * C1
__global__ void k_wm(const float* __restrict__ Wlin, float* __restrict__ Wm){
  int idx = blockIdx.x * 256 + threadIdx.x;
  if(idx >= 16 * 16384) return;
  int m = idx >> 14;
  int l = (m == 0) ? 0 : (m < 4) ? 1 : (m < 9) ? 2 : 3;
  Wm[idx] = Wlin[l * 16384 + (idx & 16383)] * C1;
}

// ---------------------------------------------------------------- CSR build
__global__ void k_count(const int* __restrict__ recv, int* __restrict__ cnt){
  int e = blockIdx.x * 256 + threadIdx.x;
  if(e < N_EDGES) atomicAdd(&cnt[recv[e]], 1);
}
__global__ void __launch_bounds__(1024) k_scan(const int* __restrict__ cnt, int* __restrict__ off){
  __shared__ int s[1024];
  int t = threadIdx.x;
  int base = t * 8;
  int loc[8]; int sum = 0;
  #pragma unroll
  for(int i = 0; i < 8; ++i){
    int idx = base + i;
    int v = (idx < N_NODES) ? cnt[idx] : 0;
    loc[i] = sum; sum += v;
  }
  s[t] = sum;
  __syncthreads();
  for(int d = 1; d < 1024; d <<= 1){
    int v = (t >= d) ? s[t - d] : 0;
    __syncthreads();
    s[t] += v;
    __syncthreads();
  }
  int excl = (t > 0) ? s[t - 1] : 0;
  #pragma unroll
  for(int i = 0; i < 8; ++i){
    int idx = base + i;
    if(idx <= N_NODES) off[idx] = excl + loc[i];
  }
}
__global__ void k_fill(const int* __restrict__ recv, const int* __restrict__ off,
                       int* __restrict__ cur, int* __restrict__ elist){
  int e = blockIdx.x * 256 + threadIdx.x;
  if(e < N_EDGES){
    int r = recv[e];
    int p = atomicAdd(&cur[r], 1);
    elist[off[r] + p] = e;
  }
}

// ---------------------------------------------------------------- K4: gather -> msg1[n][u][m]
__global__ void __launch_bounds__(256) k_gather(
    const __hip_bfloat16* __restrict__ tpw, const float* __restrict__ x,
    const float* __restrict__ ea, const int* __restrict__ send,
    const int* __restrict__ off, const int* __restrict__ elist,
    float* __restrict__ msg1){
  const int n = blockIdx.x, t = threadIdx.x;
  const int s0 = off[n], deg = off[n + 1] - s0;
  __shared__ unsigned int wr[256];   // 512 bf16
  __shared__ float xs[128];
  __shared__ float eas[16];
  float acc[8] = {0.f,0.f,0.f,0.f,0.f,0.f,0.f,0.f};
  const int u = t & 127, mg = t >> 7;
  for(int i = 0; i < deg; ++i){
    int e = elist[s0 + i];
    int snd = send[e];
    __syncthreads();
    wr[t] = ((const unsigned int*)tpw)[(size_t)e * 256 + t];
    if(t < 128) xs[t] = x[(size_t)snd * 128 + t];
    else if(t < 144) eas[t - 128] = ea[(size_t)e * 16 + (t - 128)];
    __syncthreads();
    float xu = xs[u];
    unsigned int p0 = wr[u * 2], p1 = wr[u * 2 + 1];
    float w0 = bf2f(p0 & 0xffffu), w1 = bf2f(p0 >> 16);
    float w2 = bf2f(p1 & 0xffffu), w3 = bf2f(p1 >> 16);
    if(mg == 0){                                    // m 0..7 : l = 0,1,1,1,2,2,2,2
      acc[0] += w0 * (xu * eas[0]);
      acc[1] += w1 * (xu * eas[1]);
      acc[2] += w1 * (xu * eas[2]);
      acc[3] += w1 * (xu * eas[3]);
      acc[4] += w2 * (xu * eas[4]);
      acc[5] += w2 * (xu * eas[5]);
      acc[6] += w2 * (xu * eas[6]);
      acc[7] += w2 * (xu * eas[7]);
    } else {                                        // m 8..15 : l = 2,3,3,3,3,3,3,3
      acc[0] += w2 * (xu * eas[8]);
      acc[1] += w3 * (xu * eas[9]);
      acc[2] += w3 * (xu * eas[10]);
      acc[3] += w3 * (xu * eas[11]);
      acc[4] += w3 * (xu * eas[12]);
      acc[5] += w3 * (xu * eas[13]);
      acc[6] += w3 * (xu * eas[14]);
      acc[7] += w3 * (xu * eas[15]);
    }
  }
  float4* dst = (float4*)&msg1[(size_t)n * 2048 + u * 16 + mg * 8];
  dst[0] = make_float4(acc[0], acc[1], acc[2], acc[3]);
  dst[1] = make_float4(acc[4], acc[5], acc[6], acc[7]);
}

// ---------------------------------------------------------------- K5: msg2[n][u'][m] = sum_u msg1[n][u][m] * Wm[m][u][u']
__global__ void __launch_bounds__(256) k_lin(const float* __restrict__ msg1,
                                             const float* __restrict__ Wm,
                                             float* __restrict__ msg2){
  const int nb = blockIdx.x * 8;
  __shared__ float m1[8 * 2048];    // 64KB
  const int t = threadIdx.x;
  #pragma unroll
  for(int r = 0; r < 16; ++r){
    int i4 = t + 256 * r;
    ((float4*)m1)[i4] = ((const float4*)(msg1 + (size_t)nb * 2048))[i4];
  }
  __syncthreads();
  const int m = t & 15, g = t >> 4;
  float acc[8][8];
  #pragma unroll
  for(int a = 0; a < 8; ++a)
    #pragma unroll
    for(int b = 0; b < 8; ++b) acc[a][b] = 0.f;
  const float* Wp = Wm + m * 16384 + g * 8;
  for(int k = 0; k < 128; ++k){
    float4 wa = *(const float4*)(Wp + k * 128);
    float4 wb = *(const float4*)(Wp + k * 128 + 4);
    #pragma unroll
    for(int nl = 0; nl < 8; ++nl){
      float mv = m1[nl * 2048 + k * 16 + m];
      acc[nl][0] += mv * wa.x; acc[nl][1] += mv * wa.y;
      acc[nl][2] += mv * wa.z; acc[nl][3] += mv * wa.w;
      acc[nl][4] += mv * wb.x; acc[nl][5] += mv * wb.y;
      acc[nl][6] += mv * wb.z; acc[nl][7] += mv * wb.w;
    }
  }
  #pragma unroll
  for(int nl = 0; nl < 8; ++nl)
    #pragma unroll
    for(int j = 0; j < 8; ++j)
      msg2[(size_t)(nb + nl) * 2048 + (g * 8 + j) * 16 + m] = acc[nl][j];
}

// ---------------------------------------------------------------- K6: out[n][w][m] = NORM * sum_u msg2[n][u][m] * (sum_v a[n][v] Wskip[l(m)][u][v][w])
__global__ void __launch_bounds__(256, 2) k_skip(const float* __restrict__ msg2,
                                                 const float* __restrict__ attrs,
                                                 const float* __restrict__ Wskip,
                                                 float* __restrict__ outp){
  const int nb = blockIdx.x * 8;
  __shared__ float m2[8 * 2048];    // 64KB, reused as reduction buffer
  __shared__ float at[8][12];
  const int t = threadIdx.x;
  #pragma unroll
  for(int r = 0; r < 16; ++r){
    int i4 = t + 256 * r;
    ((float4*)m2)[i4] = ((const float4*)(msg2 + (size_t)nb * 2048))[i4];
  }
  if(t < 80) at[t / 10][t % 10] = attrs[(size_t)(nb + t / 10) * 10 + t % 10];
  __syncthreads();
  const int w = t & 127, half = t >> 7;
  float acc[8][16];
  #pragma unroll
  for(int a = 0; a < 8; ++a)
    #pragma unroll
    for(int b = 0; b < 16; ++b) acc[a][b] = 0.f;
  const int u0 = half * 64;
  for(int uu = 0; uu < 64; ++uu){
    const int u = u0 + uu;
    float wv0[10], wv1[10], wv2[10], wv3[10];
    const float* Wp = Wskip + (size_t)u * 1280 + w;
    #pragma unroll
    for(int v = 0; v < 10; ++v){
      wv0[v] = Wp[v * 128];
      wv1[v] = Wp[163840 + v * 128];
      wv2[v] = Wp[327680 + v * 128];
      wv3[v] = Wp[491520 + v * 128];
    }
    #pragma unroll
    for(int nl = 0; nl < 8; ++nl){
      float s0 = 0.f, s1 = 0.f, s2 = 0.f, s3 = 0.f;
      #pragma unroll
      for(int v = 0; v < 10; ++v){
        float a = at[nl][v];
        s0 += a * wv0[v]; s1 += a * wv1[v]; s2 += a * wv2[v]; s3 += a * wv3[v];
      }
      const float4* q = (const float4*)&m2[nl * 2048 + u * 16];
      float4 q0 = q[0], q1 = q[1], q2 = q[2], q3 = q[3];
      acc[nl][0]  += q0.x * s0;
      acc[nl][1]  += q0.y * s1; acc[nl][2]  += q0.z * s1; acc[nl][3]  += q0.w * s1;
      acc[nl][4]  += q1.x * s2; acc[nl][5]  += q1.y * s2; acc[nl][6]  += q1.z * s2; acc[nl][7] += q1.w * s2;
      acc[nl][8]  += q2.x * s2;
      acc[nl][9]  += q2.y * s3; acc[nl][10] += q2.z * s3; acc[nl][11] += q2.w * s3;
      acc[nl][12] += q3.x * s3; acc[nl][13] += q3.y * s3; acc[nl][14] += q3.z * s3; acc[nl][15] += q3.w * s3;
    }
  }
  __syncthreads();
  float* red = m2;
  for(int nl = 0; nl < 8; ++nl){
    if(half == 1){
      float4* r4 = (float4*)&red[w * 16];
      r4[0] = make_float4(acc[nl][0],  acc[nl][1],  acc[nl][2],  acc[nl][3]);
      r4[1] = make_float4(acc[nl][4],  acc[nl][5],  acc[nl][6],  acc[nl][7]);
      r4[2] = make_float4(acc[nl][8],  acc[nl][9],  acc[nl][10], acc[nl][11]);
      r4[3] = make_float4(acc[nl][12], acc[nl][13], acc[nl][14], acc[nl][15]);
    }
    __syncthreads();
    if(half == 0){
      const float4* r4 = (const float4*)&red[w * 16];
      float4 b0 = r4[0], b1 = r4[1], b2 = r4[2], b3 = r4[3];
      float4 o;
      float4* dst = (float4*)&outp[(size_t)(nb + nl) * 2048 + w * 16];
      o.x = (acc[nl][0]  + b0.x) * NORM; o.y = (acc[nl][1]  + b0.y) * NORM;
      o.z = (acc[nl][2]  + b0.z) * NORM; o.w = (acc[nl][3]  + b0.w) * NORM;
      dst[0] = o;
      o.x = (acc[nl][4]  + b1.x) * NORM; o.y = (acc[nl][5]  + b1.y) * NORM;
      o.z = (acc[nl][6]  + b1.z) * NORM; o.w = (acc[nl][7]  + b1.w) * NORM;
      dst[1] = o;
      o.x = (acc[nl][8]  + b2.x) * NORM; o.y = (acc[nl][9]  + b2.y) * NORM;
      o.z = (acc[nl][10] + b2.z) * NORM; o.w = (acc[nl][11] + b2.w) * NORM;
      dst[2] = o;
      o.x = (acc[nl][12] + b3.x) * NORM; o.y = (acc[nl][13] + b3.y) * NORM;
      o.z = (acc[nl][14] + b3.z) * NORM; o.w = (acc[nl][15] + b3.w) * NORM;
      dst[3] = o;
    }
    __syncthreads();
  }
}

// ----------------------------------------------------------------
extern "C" void kernel_launch(void* const* d_in, const int* in_sizes, int n_in,
                              void* d_out, int out_size, void* d_ws, size_t ws_size,
                              hipStream_t stream){
  const float* node_attrs = (const float*)d_in[0];
  const float* node_feats = (const float*)d_in[1];
  const float* edge_attrs = (const float*)d_in[2];
  const float* edge_feats = (const float*)d_in[3];
  const int*   edge_index = (const int*)d_in[4];
  const float* cutoff     = (const float*)d_in[5];
  const float* W_up  = (const float*)d_in[6];
  const float* W1    = (const float*)d_in[7];
  const float* W2    = (const float*)d_in[8];
  const float* W3    = (const float*)d_in[9];
  const float* W4    = (const float*)d_in[10];
  const float* Wlin  = (const float*)d_in[11];
  const float* Wskip = (const float*)d_in[12];
  float* out = (float*)d_out;

  char* ws = (char*)d_ws;
  // layout (bytes): x 4,096,000 | tpw(bf16) 131,072,000 (overlaid by msg2 after K4) |
  //                 msg1 65,536,000 | Wm 1,048,576 | cnt/cur/off/elist
  float*            x     = (float*)(ws + 0);
  __hip_bfloat16*   tpw   = (__hip_bfloat16*)(ws + 4096000);
  float*            msg2  = (float*)(ws + 4096000);       // overlays tpw (dead after k_gather)
  float*            msg1  = (float*)(ws + 135168000);
  float*            Wm    = (float*)(ws + 200704000);
  int*              cnt   = (int*)(ws + 201752576);
  int*              cur   = (int*)(ws + 201784576);
  int*              offs  = (int*)(ws + 201816576);       // 8001 ints
  int*              elist = (int*)(ws + 201848640);       // 128000 ints

  hipMemsetAsync(cnt, 0, 64000, stream);  // cnt + cur

  k_up    <<<4000, 256, 0, stream>>>(node_feats, W_up, x);
  k_mlp   <<<2000, 256, 0, stream>>>(edge_feats, cutoff, W1, W2, W3, W4, tpw);
  k_wm    <<<1024, 256, 0, stream>>>(Wlin, Wm);
  k_count <<<500,  256, 0, stream>>>(edge_index + N_EDGES, cnt);
  k_scan  <<<1,   1024, 0, stream>>>(cnt, offs);
  k_fill  <<<500,  256, 0, stream>>>(edge_index + N_EDGES, offs, cur, elist);
  k_gather<<<8000, 256, 0, stream>>>(tpw, x, edge_attrs, edge_index, offs, elist, msg1);
  k_lin   <<<1000, 256, 0, stream>>>(msg1, Wm, msg2);
  k_skip  <<<1000, 256, 0, stream>>>(msg2, node_attrs, Wskip, out);
}